// Round 9
// baseline (266.197 us; speedup 1.0000x reference)
//
#include <hip/hip_runtime.h>
#include <hip/hip_bf16.h>

#define D 128        // D_IN == D_OUT == 128
#define NBMAX 512    // max buckets (N/256 <= 512 for N <= 131072)
#define CURPAD 16    // pad global cursors to one per 64B line
#define BCAP 4608    // fixed bucket capacity (mean ~4092, sigma ~64 -> +8 sigma)

typedef __attribute__((ext_vector_type(8))) short bf16x8;
typedef __attribute__((ext_vector_type(4))) float f32x4;

// fp32 -> bf16 round-to-nearest-even
__device__ inline unsigned short f2bf(float f) {
    unsigned u = __float_as_uint(f);
    u = (u + 0x7FFFu + ((u >> 16) & 1u)) >> 16;
    return (unsigned short)u;
}
__device__ inline float bf2f_lo(unsigned u) { return __uint_as_float(u << 16); }
__device__ inline float bf2f_hi(unsigned u) { return __uint_as_float(u & 0xFFFF0000u); }

// ---------------- phase 1: partition edges into padded buckets (4-replica hist) ----------------
// 1024 threads x 4 contiguous edges; rank via LDS atomics; one global atomic
// per (block,bucket) reserves the run. 4096 edges/block -> ~391 blocks.
__global__ __launch_bounds__(1024) void phase1(const int* __restrict__ rowi,
                                               const int* __restrict__ coli,
                                               const float* __restrict__ ew,
                                               int* __restrict__ bcursor,
                                               int2* __restrict__ tmp, int E) {
    __shared__ int hist[4][NBMAX];
    __shared__ int runbase[4][NBMAX];
    int tid = threadIdx.x;
    int par = tid >> 8;
    for (int i = tid; i < 4 * NBMAX; i += 1024) ((int*)hist)[i] = 0;
    __syncthreads();
    int base = blockIdx.x * 4096 + tid * 4;   // 4 contiguous edges per thread
    int col[4], row[4], rank[4]; float w[4];
    if (base + 4 <= E) {
        int4 c = *(const int4*)(coli + base);
        int4 r = *(const int4*)(rowi + base);
        float4 f = *(const float4*)(ew + base);
        col[0]=c.x; col[1]=c.y; col[2]=c.z; col[3]=c.w;
        row[0]=r.x; row[1]=r.y; row[2]=r.z; row[3]=r.w;
        w[0]=f.x; w[1]=f.y; w[2]=f.z; w[3]=f.w;
    } else {
        #pragma unroll
        for (int j = 0; j < 4; ++j) {
            int e = base + j;
            if (e < E) { col[j] = coli[e]; row[j] = rowi[e]; w[j] = ew[e]; }
            else       { col[j] = -1; }
        }
    }
    #pragma unroll
    for (int j = 0; j < 4; ++j) {
        if (col[j] >= 0) rank[j] = atomicAdd(&hist[par][col[j] >> 8], 1);
    }
    __syncthreads();
    for (int i = tid; i < NBMAX; i += 1024) {
        int c0 = hist[0][i], c1 = hist[1][i], c2 = hist[2][i], c3 = hist[3][i];
        int tot = c0 + c1 + c2 + c3;
        int b = tot ? atomicAdd(&bcursor[i * CURPAD], tot) : 0;
        runbase[0][i] = b;
        runbase[1][i] = b + c0;
        runbase[2][i] = b + c0 + c1;
        runbase[3][i] = b + c0 + c1 + c2;
    }
    __syncthreads();
    #pragma unroll
    for (int j = 0; j < 4; ++j) {
        if (col[j] >= 0) {
            int b = col[j] >> 8;
            int off = runbase[par][b] + rank[j];
            if (off < BCAP)   // overflow guard (statistically impossible)
                tmp[(size_t)b * BCAP + off] =
                    make_int2(((col[j] & 255) << 24) | row[j], __float_as_int(w[j]));
        }
    }
}

// ---------------- phase 2: per-bucket counting sort, 2-pass over L2-hot bucket ----------------
// No LDS staging (8 KB LDS -> high occupancy). Pass A counts, pass B scatters
// tmp -> sorted (separate buffer: no in-place hazard). Both passes use the
// IDENTICAL loop structure + replica attribution (capacities derive from A).
// Extra block NB does the W/bias repack (replaces the prep kernel).
__global__ __launch_bounds__(256) void phase2(const int2* __restrict__ tmp,
                                              int2* __restrict__ sorted,
                                              const int* __restrict__ bcursor,
                                              int* __restrict__ rowptr, int* __restrict__ cnt,
                                              float* __restrict__ dinv, int N, int NB,
                                              const float* __restrict__ W,
                                              bf16x8* __restrict__ gW,
                                              const float* __restrict__ bias,
                                              float* __restrict__ bias_perm) {
    int tid = threadIdx.x;
    int b = blockIdx.x;
    if (b == NB) {   // repack block: W -> bf16 B-frag layout, bias -> permuted
        for (int idx = tid; idx < 2048; idx += 256) {
            int tile = idx >> 6;
            int ln   = idx & 63;
            int kt   = tile >> 3;
            int ct   = tile & 7;
            int k0   = kt * 32 + (ln >> 4) * 8;
            int nn   = ct * 16 + (ln & 15);
            bf16x8 v;
            #pragma unroll
            for (int j = 0; j < 8; ++j) v[j] = (short)f2bf(W[(k0 + j) * D + nn]);
            gW[idx] = v;
        }
        if (tid < 128) {
            int l = tid >> 3, j = tid & 7;
            bias_perm[tid] = bias[l + 16 * j];
        }
        return;
    }
    __shared__ unsigned int cnt_s[2][256];
    __shared__ unsigned long long deg_s[2][256];
    __shared__ int scan_s[256];
    __shared__ int cur[2][256];
    int par = tid >> 7;
    cnt_s[0][tid] = 0; cnt_s[1][tid] = 0;
    deg_s[0][tid] = 0; deg_s[1][tid] = 0;
    __syncthreads();
    int count = bcursor[b * CURPAD]; if (count > BCAP) count = BCAP;
    int gbase = b * BCAP;
    // pass A: count + weighted degree
    for (int e0 = tid * 4; e0 < count; e0 += 1024) {
        int m = count - e0; if (m > 4) m = 4;
        int2 v[4];
        if (m == 4) {
            int4 q0 = *(const int4*)(tmp + gbase + e0);
            int4 q1 = *(const int4*)(tmp + gbase + e0 + 2);
            v[0] = make_int2(q0.x, q0.y); v[1] = make_int2(q0.z, q0.w);
            v[2] = make_int2(q1.x, q1.y); v[3] = make_int2(q1.z, q1.w);
        } else {
            for (int j = 0; j < m; ++j) v[j] = tmp[gbase + e0 + j];
        }
        for (int j = 0; j < m; ++j) {
            unsigned cof = ((unsigned)v[j].x) >> 24;
            atomicAdd(&cnt_s[par][cof], 1u);
            atomicAdd(&deg_s[par][cof],
                (unsigned long long)(__int_as_float(v[j].y) * 1048576.0f + 0.5f));
        }
    }
    __syncthreads();
    int c0 = (int)cnt_s[0][tid];
    int v0 = c0 + (int)cnt_s[1][tid];
    scan_s[tid] = v0; __syncthreads();
    for (int off = 1; off < 256; off <<= 1) {
        int t = (tid >= off) ? scan_s[tid - off] : 0;
        __syncthreads(); scan_s[tid] += t; __syncthreads();
    }
    int excl = scan_s[tid] - v0;
    int node = b * 256 + tid;
    if (node < N) {
        rowptr[node] = gbase + excl;
        cnt[node] = v0;
        unsigned long long dsum = deg_s[0][tid] + deg_s[1][tid];
        float deg = 1.0f + (float)((double)dsum * (1.0 / 1048576.0));
        dinv[node] = rsqrtf(deg);   // deg >= 1 (self-loop)
    }
    cur[0][tid] = gbase + excl;
    cur[1][tid] = gbase + excl + c0;
    __syncthreads();
    // pass B: scatter (same structure & par attribution as pass A; L2-hot reads)
    int glimit = gbase + count;
    for (int e0 = tid * 4; e0 < count; e0 += 1024) {
        int m = count - e0; if (m > 4) m = 4;
        int2 v[4];
        if (m == 4) {
            int4 q0 = *(const int4*)(tmp + gbase + e0);
            int4 q1 = *(const int4*)(tmp + gbase + e0 + 2);
            v[0] = make_int2(q0.x, q0.y); v[1] = make_int2(q0.z, q0.w);
            v[2] = make_int2(q1.x, q1.y); v[3] = make_int2(q1.z, q1.w);
        } else {
            for (int j = 0; j < m; ++j) v[j] = tmp[gbase + e0 + j];
        }
        for (int j = 0; j < m; ++j) {
            unsigned cof = ((unsigned)v[j].x) >> 24;
            int pos = atomicAdd(&cur[par][cof], 1);
            if (pos < glimit) sorted[pos] = make_int2(v[j].x & 0xFFFFFF, v[j].y);
        }
    }
}

// ---------------- yw = dinv .* (x @ W), bf16, PERMUTED cols: col' = m16*8 + ct ----------------
__global__ __launch_bounds__(256) void gemm_mfma(const float* __restrict__ x,
                                                 const bf16x8* __restrict__ gW,
                                                 const float* __restrict__ dinv,
                                                 unsigned short* __restrict__ yw, int N) {
    int tid  = threadIdx.x;
    int wid  = tid >> 6;
    int lane = tid & 63;
    int quad = lane >> 4;
    int m16  = lane & 15;
    int row0 = blockIdx.x * 64 + wid * 16;
    int row  = row0 + m16;

    f32x4 acc[8];
    #pragma unroll
    for (int ct = 0; ct < 8; ++ct) acc[ct] = (f32x4){0.f, 0.f, 0.f, 0.f};

    #pragma unroll
    for (int kt = 0; kt < 4; ++kt) {
        bf16x8 a;
        if (row < N) {
            const float* xp = x + (size_t)row * D + kt * 32 + quad * 8;
            float4 u0 = *(const float4*)xp;
            float4 u1 = *(const float4*)(xp + 4);
            a[0] = (short)f2bf(u0.x); a[1] = (short)f2bf(u0.y);
            a[2] = (short)f2bf(u0.z); a[3] = (short)f2bf(u0.w);
            a[4] = (short)f2bf(u1.x); a[5] = (short)f2bf(u1.y);
            a[6] = (short)f2bf(u1.z); a[7] = (short)f2bf(u1.w);
        } else {
            #pragma unroll
            for (int j = 0; j < 8; ++j) a[j] = 0;
        }
        #pragma unroll
        for (int ct = 0; ct < 8; ++ct) {
            acc[ct] = __builtin_amdgcn_mfma_f32_16x16x32_bf16(
                a, gW[(kt * 8 + ct) * 64 + lane], acc[ct], 0, 0, 0);
        }
    }

    // C layout: orig col = m16 + 16*ct, row = row0 + quad*4 + i.
    // Permuted store: yw[row][m16*8 + ct] -> one dwordx4 per row per lane.
    int rq = row0 + quad * 4;
    #pragma unroll
    for (int i = 0; i < 4; ++i) {
        int r = rq + i;
        if (r < N) {
            float sc = dinv[r];
            unsigned p0 = (unsigned)f2bf(sc * acc[0][i]) | ((unsigned)f2bf(sc * acc[1][i]) << 16);
            unsigned p1 = (unsigned)f2bf(sc * acc[2][i]) | ((unsigned)f2bf(sc * acc[3][i]) << 16);
            unsigned p2 = (unsigned)f2bf(sc * acc[4][i]) | ((unsigned)f2bf(sc * acc[5][i]) << 16);
            unsigned p3 = (unsigned)f2bf(sc * acc[6][i]) | ((unsigned)f2bf(sc * acc[7][i]) << 16);
            *(uint4*)(yw + (size_t)r * D + m16 * 8) = make_uint4(p0, p1, p2, p3);
        }
    }
}

// ---------------- aggregation: wave per node, 4 edge-groups x 16 lanes ----------------
__global__ __launch_bounds__(256) void aggregate(const unsigned short* __restrict__ yw,
                                                 const float* __restrict__ dinv,
                                                 const int* __restrict__ rowptr,
                                                 const int* __restrict__ cnt,
                                                 const int2* __restrict__ sorted,
                                                 const float* __restrict__ bias_perm,
                                                 const float* __restrict__ prelu_a,
                                                 float* __restrict__ out, int N) {
    int wid  = threadIdx.x >> 6;
    int lane = threadIdx.x & 63;
    int n = blockIdx.x * 4 + wid;
    if (n >= N) return;
    int g = lane >> 4;       // edge subgroup 0..3
    int l = lane & 15;       // feature subgroup: ushorts l*8 .. l*8+7
    float2 a0 = {0.f,0.f}, a1 = {0.f,0.f}, a2 = {0.f,0.f}, a3 = {0.f,0.f};
    int s = rowptr[n];
    int cn = cnt[n];
    for (int base = 0; base < cn; base += 64) {
        int rem = cn - base;
        int m = rem < 64 ? rem : 64;
        int2 er = make_int2(0, 0);
        if (lane < rem) er = sorted[s + base + lane];
        float ewv = __int_as_float(er.y);
        int idx = g;
        int   r0 = __shfl(er.x, idx);
        float w0 = __shfl(ewv, idx);
        if (idx >= m) w0 = 0.f;
        uint4 v0 = *(const uint4*)(yw + (size_t)r0 * D + l * 8);
        for (int j = 4; j < m; j += 4) {
            int idx1 = j + g;
            int   r1 = __shfl(er.x, idx1);
            float w1 = __shfl(ewv, idx1);
            if (idx1 >= m) w1 = 0.f;
            uint4 v1 = *(const uint4*)(yw + (size_t)r1 * D + l * 8);
            a0.x = fmaf(w0, bf2f_lo(v0.x), a0.x); a0.y = fmaf(w0, bf2f_hi(v0.x), a0.y);
            a1.x = fmaf(w0, bf2f_lo(v0.y), a1.x); a1.y = fmaf(w0, bf2f_hi(v0.y), a1.y);
            a2.x = fmaf(w0, bf2f_lo(v0.z), a2.x); a2.y = fmaf(w0, bf2f_hi(v0.z), a2.y);
            a3.x = fmaf(w0, bf2f_lo(v0.w), a3.x); a3.y = fmaf(w0, bf2f_hi(v0.w), a3.y);
            v0 = v1; w0 = w1;
        }
        a0.x = fmaf(w0, bf2f_lo(v0.x), a0.x); a0.y = fmaf(w0, bf2f_hi(v0.x), a0.y);
        a1.x = fmaf(w0, bf2f_lo(v0.y), a1.x); a1.y = fmaf(w0, bf2f_hi(v0.y), a1.y);
        a2.x = fmaf(w0, bf2f_lo(v0.z), a2.x); a2.y = fmaf(w0, bf2f_hi(v0.z), a2.y);
        a3.x = fmaf(w0, bf2f_lo(v0.w), a3.x); a3.y = fmaf(w0, bf2f_hi(v0.w), a3.y);
    }
    // reduce across the 4 edge-groups
    a0.x += __shfl_xor(a0.x, 16); a0.y += __shfl_xor(a0.y, 16);
    a1.x += __shfl_xor(a1.x, 16); a1.y += __shfl_xor(a1.y, 16);
    a2.x += __shfl_xor(a2.x, 16); a2.y += __shfl_xor(a2.y, 16);
    a3.x += __shfl_xor(a3.x, 16); a3.y += __shfl_xor(a3.y, 16);
    a0.x += __shfl_xor(a0.x, 32); a0.y += __shfl_xor(a0.y, 32);
    a1.x += __shfl_xor(a1.x, 32); a1.y += __shfl_xor(a1.y, 32);
    a2.x += __shfl_xor(a2.x, 32); a2.y += __shfl_xor(a2.y, 32);
    a3.x += __shfl_xor(a3.x, 32); a3.y += __shfl_xor(a3.y, 32);

    if (lane < 16) {
        uint4 sv = *(const uint4*)(yw + (size_t)n * D + lane * 8);   // self term
        a0.x += bf2f_lo(sv.x); a0.y += bf2f_hi(sv.x);
        a1.x += bf2f_lo(sv.y); a1.y += bf2f_hi(sv.y);
        a2.x += bf2f_lo(sv.z); a2.y += bf2f_hi(sv.z);
        a3.x += bf2f_lo(sv.w); a3.y += bf2f_hi(sv.w);
        float di = dinv[n];
        float pa = prelu_a[0];
        float4 b0 = *(const float4*)(bias_perm + lane * 8);
        float4 b1 = *(const float4*)(bias_perm + lane * 8 + 4);
        float av[8] = {a0.x, a0.y, a1.x, a1.y, a2.x, a2.y, a3.x, a3.y};
        float bb[8] = {b0.x, b0.y, b0.z, b0.w, b1.x, b1.y, b1.z, b1.w};
        float* op = out + (size_t)n * D + lane;
        #pragma unroll
        for (int j = 0; j < 8; ++j) {
            float v = fmaf(di, av[j], bb[j]);
            v = (v >= 0.f) ? v : pa * v;
            op[16 * j] = v;   // 16 lanes x 4B = full 64B line per j
        }
    }
}

extern "C" void kernel_launch(void* const* d_in, const int* in_sizes, int n_in,
                              void* d_out, int out_size, void* d_ws, size_t ws_size,
                              hipStream_t stream) {
    const float* x       = (const float*)d_in[0];
    const int*   ei      = (const int*)d_in[1];   // [2, E] int32
    const float* ew      = (const float*)d_in[2];
    const float* W       = (const float*)d_in[3];
    const float* bias    = (const float*)d_in[4];
    const float* prelu_a = (const float*)d_in[5];
    float* out = (float*)d_out;

    int N = in_sizes[0] / D;
    int E = in_sizes[2];
    const int* rowi = ei;       // source
    const int* coli = ei + E;   // target
    int NB = (N + 255) >> 8;    // buckets of 256 nodes

    // workspace layout. yw ALIASES tmp: tmp is dead once phase2 completes,
    // and gemm (which writes yw) runs strictly after phase2.
    char* ws = (char*)d_ws;
    size_t o = 0;
    int2* sorted = (int2*)(ws + o); o += (size_t)NB * BCAP * 8;             // 14.4 MB
    size_t xbase = o;
    int2* tmp = (int2*)(ws + xbase);
    unsigned short* yw = (unsigned short*)(ws + xbase);
    size_t tmp_sz = (size_t)NB * BCAP * 8;
    size_t yw_sz  = (size_t)N * D * 2;
    o += (tmp_sz > yw_sz ? tmp_sz : yw_sz);                                 // 25.6 MB
    o = (o + 255) & ~(size_t)255;
    bf16x8* gW   = (bf16x8*)(ws + o); o += 2048 * 16;                       // 32 KB
    float* bias_perm = (float*)(ws + o); o += D * 4;
    int* bcursor = (int*)(ws + o); o += (size_t)NB * CURPAD * 4;
    o = (o + 255) & ~(size_t)255;
    int* rowptr  = (int*)(ws + o); o += (size_t)N * 4;
    int* cnt     = (int*)(ws + o); o += (size_t)N * 4;
    float* dinv  = (float*)(ws + o); o += (size_t)N * 4;

    hipMemsetAsync(bcursor, 0, (size_t)NB * CURPAD * 4, stream);
    phase1<<<(E + 4095) / 4096, 1024, 0, stream>>>(rowi, coli, ew, bcursor, tmp, E);
    phase2<<<NB + 1, 256, 0, stream>>>(tmp, sorted, bcursor, rowptr, cnt, dinv, N, NB,
                                       W, gW, bias, bias_perm);
    gemm_mfma<<<(N + 63) / 64, 256, 0, stream>>>(x, gW, dinv, yw, N);
    aggregate<<<(N + 3) / 4, 256, 0, stream>>>(yw, dinv, rowptr, cnt, sorted, bias_perm, prelu_a, out, N);
}

// Round 10
// 219.089 us; speedup vs baseline: 1.2150x; 1.2150x over previous
//
#include <hip/hip_runtime.h>
#include <hip/hip_bf16.h>

#define D 128        // D_IN == D_OUT == 128
#define NBMAX 512    // max buckets (N/256 <= 512 for N <= 131072)
#define CURPAD 16    // pad global cursors to one per 64B line
#define BCAP 6144    // fixed bucket capacity (mean ~4092, sigma ~64 -> +32 sigma)

typedef __attribute__((ext_vector_type(8))) short bf16x8;
typedef __attribute__((ext_vector_type(4))) float f32x4;

// fp32 -> bf16 round-to-nearest-even
__device__ inline unsigned short f2bf(float f) {
    unsigned u = __float_as_uint(f);
    u = (u + 0x7FFFu + ((u >> 16) & 1u)) >> 16;
    return (unsigned short)u;
}
__device__ inline float bf2f_lo(unsigned u) { return __uint_as_float(u << 16); }
__device__ inline float bf2f_hi(unsigned u) { return __uint_as_float(u & 0xFFFF0000u); }

// ---------------- phase 1: partition edges into padded buckets (4-replica hist) ----------------
// 1024 threads x 8 contiguous edges (R8 geometry). Extra block nbE does the
// W/bias repack (dispatch completes before phase2 starts -> no race on gW).
__global__ __launch_bounds__(1024) void phase1(const int* __restrict__ rowi,
                                               const int* __restrict__ coli,
                                               const float* __restrict__ ew,
                                               int* __restrict__ bcursor,
                                               int2* __restrict__ tmp, int E, int nbE,
                                               const float* __restrict__ W,
                                               bf16x8* __restrict__ gW,
                                               const float* __restrict__ bias,
                                               float* __restrict__ bias_perm) {
    int tid = threadIdx.x;
    if (blockIdx.x == nbE) {   // repack block
        for (int idx = tid; idx < 2048; idx += 1024) {
            int tile = idx >> 6;
            int ln   = idx & 63;
            int kt   = tile >> 3;
            int ct   = tile & 7;
            int k0   = kt * 32 + (ln >> 4) * 8;
            int nn   = ct * 16 + (ln & 15);
            bf16x8 v;
            #pragma unroll
            for (int j = 0; j < 8; ++j) v[j] = (short)f2bf(W[(k0 + j) * D + nn]);
            gW[idx] = v;
        }
        if (tid < 128) {
            int l = tid >> 3, j = tid & 7;
            bias_perm[tid] = bias[l + 16 * j];
        }
        return;
    }
    __shared__ int hist[4][NBMAX];
    __shared__ int runbase[4][NBMAX];
    int par = tid >> 8;
    for (int i = tid; i < 4 * NBMAX; i += 1024) ((int*)hist)[i] = 0;
    __syncthreads();
    int base = blockIdx.x * 8192 + tid * 8;   // 8 contiguous edges per thread
    int col[8], row[8], rank[8]; float w[8];
    if (base + 8 <= E) {
        int4 c0 = *(const int4*)(coli + base), c1 = *(const int4*)(coli + base + 4);
        int4 r0 = *(const int4*)(rowi + base), r1 = *(const int4*)(rowi + base + 4);
        float4 w0 = *(const float4*)(ew + base), w1 = *(const float4*)(ew + base + 4);
        col[0]=c0.x; col[1]=c0.y; col[2]=c0.z; col[3]=c0.w;
        col[4]=c1.x; col[5]=c1.y; col[6]=c1.z; col[7]=c1.w;
        row[0]=r0.x; row[1]=r0.y; row[2]=r0.z; row[3]=r0.w;
        row[4]=r1.x; row[5]=r1.y; row[6]=r1.z; row[7]=r1.w;
        w[0]=w0.x; w[1]=w0.y; w[2]=w0.z; w[3]=w0.w;
        w[4]=w1.x; w[5]=w1.y; w[6]=w1.z; w[7]=w1.w;
    } else {
        #pragma unroll
        for (int j = 0; j < 8; ++j) {
            int e = base + j;
            if (e < E) { col[j] = coli[e]; row[j] = rowi[e]; w[j] = ew[e]; }
            else       { col[j] = -1; }
        }
    }
    #pragma unroll
    for (int j = 0; j < 8; ++j) {
        if (col[j] >= 0) rank[j] = atomicAdd(&hist[par][col[j] >> 8], 1);
    }
    __syncthreads();
    for (int i = tid; i < NBMAX; i += 1024) {
        int c0 = hist[0][i], c1 = hist[1][i], c2 = hist[2][i], c3 = hist[3][i];
        int tot = c0 + c1 + c2 + c3;
        int b = tot ? atomicAdd(&bcursor[i * CURPAD], tot) : 0;
        runbase[0][i] = b;
        runbase[1][i] = b + c0;
        runbase[2][i] = b + c0 + c1;
        runbase[3][i] = b + c0 + c1 + c2;
    }
    __syncthreads();
    #pragma unroll
    for (int j = 0; j < 8; ++j) {
        if (col[j] >= 0) {
            int b = col[j] >> 8;
            int off = runbase[par][b] + rank[j];
            if (off < BCAP)   // overflow guard (statistically impossible)
                tmp[(size_t)b * BCAP + off] =
                    make_int2(((col[j] & 255) << 24) | row[j], __float_as_int(w[j]));
        }
    }
}

// ---------------- phase 2: per-bucket counting sort (LDS-staged, in-place) + fused gemm ----------------
// R8-verbatim sort: count loop and scatter loop use the SAME pairwise structure
// and replica (par) attribution. After the sort, the SAME block runs the
// 256-row MFMA gemm for its nodes: yw[r] = dinv[r] .* (x[r] @ W), bf16,
// column-PERMUTED (col' = m16*8 + ct). gW is staged into the dead ebuf LDS.
__global__ __launch_bounds__(256) void phase2(int2* __restrict__ tmp,
                                              const int* __restrict__ bcursor,
                                              int* __restrict__ rowptr, int* __restrict__ cnt,
                                              float* __restrict__ dinv, int N,
                                              const float* __restrict__ x,
                                              const bf16x8* __restrict__ gW,
                                              unsigned short* __restrict__ yw) {
    __shared__ int2 ebuf[BCAP];                   // 48 KB bucket staging (reused for gW)
    __shared__ unsigned int cnt_s[2][256];
    __shared__ unsigned long long deg_s[2][256];
    __shared__ int scan_s[256];
    __shared__ int cur[2][256];
    __shared__ float dinv_s[256];
    int tid = threadIdx.x;
    int par = tid >> 7;
    cnt_s[0][tid] = 0; cnt_s[1][tid] = 0;
    deg_s[0][tid] = 0; deg_s[1][tid] = 0;
    __syncthreads();
    int b = blockIdx.x;
    int count = bcursor[b * CURPAD]; if (count > BCAP) count = BCAP;
    int gbase = b * BCAP;
    // load bucket -> LDS, accumulate per-node cnt + weighted degree (pairwise)
    for (int e = tid * 2; e < count; e += 512) {
        if (e + 1 < count) {
            int4 q = *(const int4*)(tmp + gbase + e);
            int2 v0 = make_int2(q.x, q.y), v1 = make_int2(q.z, q.w);
            ebuf[e] = v0; ebuf[e + 1] = v1;
            unsigned cof0 = ((unsigned)v0.x) >> 24, cof1 = ((unsigned)v1.x) >> 24;
            atomicAdd(&cnt_s[par][cof0], 1u);
            atomicAdd(&cnt_s[par][cof1], 1u);
            atomicAdd(&deg_s[par][cof0],
                (unsigned long long)(__int_as_float(v0.y) * 1048576.0f + 0.5f));
            atomicAdd(&deg_s[par][cof1],
                (unsigned long long)(__int_as_float(v1.y) * 1048576.0f + 0.5f));
        } else {
            int2 v = tmp[gbase + e];
            ebuf[e] = v;
            unsigned cof = ((unsigned)v.x) >> 24;
            atomicAdd(&cnt_s[par][cof], 1u);
            atomicAdd(&deg_s[par][cof],
                (unsigned long long)(__int_as_float(v.y) * 1048576.0f + 0.5f));
        }
    }
    __syncthreads();
    int c0 = (int)cnt_s[0][tid];
    int v0 = c0 + (int)cnt_s[1][tid];
    scan_s[tid] = v0; __syncthreads();
    for (int off = 1; off < 256; off <<= 1) {
        int t = (tid >= off) ? scan_s[tid - off] : 0;
        __syncthreads(); scan_s[tid] += t; __syncthreads();
    }
    int excl = scan_s[tid] - v0;
    int node = b * 256 + tid;
    {
        unsigned long long dsum = deg_s[0][tid] + deg_s[1][tid];
        float deg = 1.0f + (float)((double)dsum * (1.0 / 1048576.0));
        float dv = rsqrtf(deg);   // deg >= 1 (self-loop)
        dinv_s[tid] = dv;
        if (node < N) {
            rowptr[node] = gbase + excl;
            cnt[node] = v0;
            dinv[node] = dv;
        }
    }
    cur[0][tid] = gbase + excl;
    cur[1][tid] = gbase + excl + c0;
    __syncthreads();
    // scatter back into tmp: SAME pairwise structure & par attribution as count
    int glimit = gbase + count;
    for (int e = tid * 2; e < count; e += 512) {
        int2 v = ebuf[e];
        unsigned coff = ((unsigned)v.x) >> 24;
        int pos = atomicAdd(&cur[par][coff], 1);
        if (pos < glimit) tmp[pos] = make_int2(v.x & 0xFFFFFF, v.y);
        if (e + 1 < count) {
            int2 v1 = ebuf[e + 1];
            unsigned cof1 = ((unsigned)v1.x) >> 24;
            int pos1 = atomicAdd(&cur[par][cof1], 1);
            if (pos1 < glimit) tmp[pos1] = make_int2(v1.x & 0xFFFFFF, v1.y);
        }
    }
    __syncthreads();   // ebuf reads done -> safe to repurpose as smW

    // ---- fused gemm for rows [b*256, b*256+256) ----
    bf16x8* smW = (bf16x8*)ebuf;   // 32 KB of the dead 48 KB staging buffer
    for (int idx = tid; idx < 2048; idx += 256) smW[idx] = gW[idx];
    __syncthreads();
    int wid  = tid >> 6;
    int lane = tid & 63;
    int quad = lane >> 4;
    int m16  = lane & 15;
    #pragma unroll
    for (int rb = 0; rb < 4; ++rb) {
        int row0 = b * 256 + rb * 64 + wid * 16;
        int row  = row0 + m16;
        f32x4 acc[8];
        #pragma unroll
        for (int ct = 0; ct < 8; ++ct) acc[ct] = (f32x4){0.f, 0.f, 0.f, 0.f};
        #pragma unroll
        for (int kt = 0; kt < 4; ++kt) {
            bf16x8 a;
            if (row < N) {
                const float* xp = x + (size_t)row * D + kt * 32 + quad * 8;
                float4 u0 = *(const float4*)xp;
                float4 u1 = *(const float4*)(xp + 4);
                a[0] = (short)f2bf(u0.x); a[1] = (short)f2bf(u0.y);
                a[2] = (short)f2bf(u0.z); a[3] = (short)f2bf(u0.w);
                a[4] = (short)f2bf(u1.x); a[5] = (short)f2bf(u1.y);
                a[6] = (short)f2bf(u1.z); a[7] = (short)f2bf(u1.w);
            } else {
                #pragma unroll
                for (int j = 0; j < 8; ++j) a[j] = 0;
            }
            #pragma unroll
            for (int ct = 0; ct < 8; ++ct) {
                acc[ct] = __builtin_amdgcn_mfma_f32_16x16x32_bf16(
                    a, smW[(kt * 8 + ct) * 64 + lane], acc[ct], 0, 0, 0);
            }
        }
        // C layout: orig col = m16 + 16*ct, row = row0 + quad*4 + i.
        // Permuted store: yw[row][m16*8 + ct] -> one dwordx4 per row per lane.
        int rq = row0 + quad * 4;
        #pragma unroll
        for (int i = 0; i < 4; ++i) {
            int r = rq + i;
            if (r < N) {
                float sc = dinv_s[r - b * 256];
                unsigned p0 = (unsigned)f2bf(sc * acc[0][i]) | ((unsigned)f2bf(sc * acc[1][i]) << 16);
                unsigned p1 = (unsigned)f2bf(sc * acc[2][i]) | ((unsigned)f2bf(sc * acc[3][i]) << 16);
                unsigned p2 = (unsigned)f2bf(sc * acc[4][i]) | ((unsigned)f2bf(sc * acc[5][i]) << 16);
                unsigned p3 = (unsigned)f2bf(sc * acc[6][i]) | ((unsigned)f2bf(sc * acc[7][i]) << 16);
                *(uint4*)(yw + (size_t)r * D + m16 * 8) = make_uint4(p0, p1, p2, p3);
            }
        }
    }
}

// ---------------- aggregation: wave per node, 4 edge-groups x 16 lanes ----------------
__global__ __launch_bounds__(256) void aggregate(const unsigned short* __restrict__ yw,
                                                 const float* __restrict__ dinv,
                                                 const int* __restrict__ rowptr,
                                                 const int* __restrict__ cnt,
                                                 const int2* __restrict__ sorted,
                                                 const float* __restrict__ bias_perm,
                                                 const float* __restrict__ prelu_a,
                                                 float* __restrict__ out, int N) {
    int wid  = threadIdx.x >> 6;
    int lane = threadIdx.x & 63;
    int n = blockIdx.x * 4 + wid;
    if (n >= N) return;
    int g = lane >> 4;       // edge subgroup 0..3
    int l = lane & 15;       // feature subgroup: ushorts l*8 .. l*8+7
    float2 a0 = {0.f,0.f}, a1 = {0.f,0.f}, a2 = {0.f,0.f}, a3 = {0.f,0.f};
    int s = rowptr[n];
    int cn = cnt[n];
    for (int base = 0; base < cn; base += 64) {
        int rem = cn - base;
        int m = rem < 64 ? rem : 64;
        int2 er = make_int2(0, 0);
        if (lane < rem) er = sorted[s + base + lane];
        float ewv = __int_as_float(er.y);
        int idx = g;
        int   r0 = __shfl(er.x, idx);
        float w0 = __shfl(ewv, idx);
        if (idx >= m) w0 = 0.f;
        uint4 v0 = *(const uint4*)(yw + (size_t)r0 * D + l * 8);
        for (int j = 4; j < m; j += 4) {
            int idx1 = j + g;
            int   r1 = __shfl(er.x, idx1);
            float w1 = __shfl(ewv, idx1);
            if (idx1 >= m) w1 = 0.f;
            uint4 v1 = *(const uint4*)(yw + (size_t)r1 * D + l * 8);
            a0.x = fmaf(w0, bf2f_lo(v0.x), a0.x); a0.y = fmaf(w0, bf2f_hi(v0.x), a0.y);
            a1.x = fmaf(w0, bf2f_lo(v0.y), a1.x); a1.y = fmaf(w0, bf2f_hi(v0.y), a1.y);
            a2.x = fmaf(w0, bf2f_lo(v0.z), a2.x); a2.y = fmaf(w0, bf2f_hi(v0.z), a2.y);
            a3.x = fmaf(w0, bf2f_lo(v0.w), a3.x); a3.y = fmaf(w0, bf2f_hi(v0.w), a3.y);
            v0 = v1; w0 = w1;
        }
        a0.x = fmaf(w0, bf2f_lo(v0.x), a0.x); a0.y = fmaf(w0, bf2f_hi(v0.x), a0.y);
        a1.x = fmaf(w0, bf2f_lo(v0.y), a1.x); a1.y = fmaf(w0, bf2f_hi(v0.y), a1.y);
        a2.x = fmaf(w0, bf2f_lo(v0.z), a2.x); a2.y = fmaf(w0, bf2f_hi(v0.z), a2.y);
        a3.x = fmaf(w0, bf2f_lo(v0.w), a3.x); a3.y = fmaf(w0, bf2f_hi(v0.w), a3.y);
    }
    // reduce across the 4 edge-groups
    a0.x += __shfl_xor(a0.x, 16); a0.y += __shfl_xor(a0.y, 16);
    a1.x += __shfl_xor(a1.x, 16); a1.y += __shfl_xor(a1.y, 16);
    a2.x += __shfl_xor(a2.x, 16); a2.y += __shfl_xor(a2.y, 16);
    a3.x += __shfl_xor(a3.x, 16); a3.y += __shfl_xor(a3.y, 16);
    a0.x += __shfl_xor(a0.x, 32); a0.y += __shfl_xor(a0.y, 32);
    a1.x += __shfl_xor(a1.x, 32); a1.y += __shfl_xor(a1.y, 32);
    a2.x += __shfl_xor(a2.x, 32); a2.y += __shfl_xor(a2.y, 32);
    a3.x += __shfl_xor(a3.x, 32); a3.y += __shfl_xor(a3.y, 32);

    if (lane < 16) {
        uint4 sv = *(const uint4*)(yw + (size_t)n * D + lane * 8);   // self term
        a0.x += bf2f_lo(sv.x); a0.y += bf2f_hi(sv.x);
        a1.x += bf2f_lo(sv.y); a1.y += bf2f_hi(sv.y);
        a2.x += bf2f_lo(sv.z); a2.y += bf2f_hi(sv.z);
        a3.x += bf2f_lo(sv.w); a3.y += bf2f_hi(sv.w);
        float di = dinv[n];
        float pa = prelu_a[0];
        float4 b0 = *(const float4*)(bias_perm + lane * 8);
        float4 b1 = *(const float4*)(bias_perm + lane * 8 + 4);
        float av[8] = {a0.x, a0.y, a1.x, a1.y, a2.x, a2.y, a3.x, a3.y};
        float bb[8] = {b0.x, b0.y, b0.z, b0.w, b1.x, b1.y, b1.z, b1.w};
        float* op = out + (size_t)n * D + lane;
        #pragma unroll
        for (int j = 0; j < 8; ++j) {
            float v = fmaf(di, av[j], bb[j]);
            v = (v >= 0.f) ? v : pa * v;
            op[16 * j] = v;   // 16 lanes x 4B = full 64B line per j
        }
    }
}

extern "C" void kernel_launch(void* const* d_in, const int* in_sizes, int n_in,
                              void* d_out, int out_size, void* d_ws, size_t ws_size,
                              hipStream_t stream) {
    const float* x       = (const float*)d_in[0];
    const int*   ei      = (const int*)d_in[1];   // [2, E] int32
    const float* ew      = (const float*)d_in[2];
    const float* W       = (const float*)d_in[3];
    const float* bias    = (const float*)d_in[4];
    const float* prelu_a = (const float*)d_in[5];
    float* out = (float*)d_out;

    int N = in_sizes[0] / D;
    int E = in_sizes[2];
    const int* rowi = ei;       // source
    const int* coli = ei + E;   // target
    int NB = (N + 255) >> 8;    // buckets of 256 nodes
    int nbE = (E + 8191) / 8192;

    // workspace layout (R8 layout, no aliasing)
    char* ws = (char*)d_ws;
    size_t o = 0;
    int2*  tmp = (int2*)(ws + o); o += (size_t)NB * BCAP * 8;               // ~19 MB
    unsigned short* yw = (unsigned short*)(ws + o); o += (size_t)N * D * 2; // 25.6 MB
    bf16x8* gW   = (bf16x8*)(ws + o); o += 2048 * 16;                       // 32 KB
    float* bias_perm = (float*)(ws + o); o += D * 4;
    int* bcursor = (int*)(ws + o); o += (size_t)NB * CURPAD * 4;
    o = (o + 255) & ~(size_t)255;
    int* rowptr  = (int*)(ws + o); o += (size_t)N * 4;
    int* cnt     = (int*)(ws + o); o += (size_t)N * 4;
    float* dinv  = (float*)(ws + o); o += (size_t)N * 4;

    hipMemsetAsync(bcursor, 0, (size_t)NB * CURPAD * 4, stream);
    phase1<<<nbE + 1, 1024, 0, stream>>>(rowi, coli, ew, bcursor, tmp, E, nbE,
                                         W, gW, bias, bias_perm);
    phase2<<<NB, 256, 0, stream>>>(tmp, bcursor, rowptr, cnt, dinv, N, x, gW, yw);
    aggregate<<<(N + 3) / 4, 256, 0, stream>>>(yw, dinv, rowptr, cnt, tmp, bias_perm, prelu_a, out, N);
}